// Round 1
// baseline (868.974 us; speedup 1.0000x reference)
//
#include <hip/hip_runtime.h>
#include <hip/hip_bf16.h>
#include <cstdint>
#include <cstddef>

// ---------- types / helpers ----------
typedef __attribute__((ext_vector_type(8))) short  bf16x8;
typedef __attribute__((ext_vector_type(4))) float  f32x4;

#define DEVINL __device__ __forceinline__

DEVINL unsigned short f2bf(float f) {
  unsigned int u = __float_as_uint(f);
  u += 0x7fff + ((u >> 16) & 1);   // round-to-nearest-even
  return (unsigned short)(u >> 16);
}

// global -> LDS staging: 16B per lane. lds_u must be wave-uniform; HW adds lane*16.
DEVINL void stage16(const unsigned short* __restrict__ g, unsigned short* lds_u, int lane) {
#if defined(__has_builtin) && __has_builtin(__builtin_amdgcn_global_load_lds)
  (void)lane;
  __builtin_amdgcn_global_load_lds((const __attribute__((address_space(1))) void*)g,
                                   (__attribute__((address_space(3))) void*)lds_u, 16, 0, 0);
#else
  bf16x8 v = *reinterpret_cast<const bf16x8*>(g);
  *reinterpret_cast<bf16x8*>(lds_u + (size_t)lane * 8) = v;
#endif
}

// ---------- elementwise conversions ----------
__global__ void k_cvt_x(const float* __restrict__ x, unsigned short* __restrict__ o, int n) {
  int i = (blockIdx.x * blockDim.x + threadIdx.x) * 4;
  if (i >= n) return;
  float4 v = *reinterpret_cast<const float4*>(x + i);
  ushort4 r;
  r.x = f2bf(v.x); r.y = f2bf(v.y); r.z = f2bf(v.z); r.w = f2bf(v.w);
  *reinterpret_cast<ushort4*>(o + i) = r;
}

// W[K][N] fp32 -> WT[N][K] bf16 (tiled transpose)
__global__ void k_tw(const float* __restrict__ W, unsigned short* __restrict__ WT, int K, int N) {
  __shared__ float t[32][33];
  int n0 = blockIdx.x * 32, k0 = blockIdx.y * 32;
  int tx = threadIdx.x, ty = threadIdx.y;  // (32,8)
#pragma unroll
  for (int j = 0; j < 4; j++)
    t[ty + j * 8][tx] = W[(size_t)(k0 + ty + j * 8) * N + n0 + tx];
  __syncthreads();
#pragma unroll
  for (int j = 0; j < 4; j++)
    WT[(size_t)(n0 + ty + j * 8) * K + k0 + tx] = f2bf(t[tx][ty + j * 8]);
}

// ---------- GEMM: C[M][N] = A[M][K](bf16) * W[K][N](as WT[N][K] bf16) + bias ----------
// MODE 0: bf16 plain [M][N]
// MODE 1: bf16 heads scatter -> buf[((b*16+h)*2048+t)*160 + d], h=col>>7, d=col&127
// MODE 2: bf16 Vt scatter    -> buf[((b*16+h)*128 + d)*2048 + t]
// MODE 3: fp32 plain [M][N]
template <int MODE>
__global__ __launch_bounds__(256) void k_gemm(const unsigned short* __restrict__ A,
                                              const unsigned short* __restrict__ BT,
                                              const float* __restrict__ bias,
                                              void* __restrict__ out, int N, int K) {
  __shared__ unsigned short sA[128 * 64];
  __shared__ unsigned short sB[128 * 64];
  const int tid = threadIdx.x;
  const int lane = tid & 63, wid = tid >> 6;
  const int wr = wid >> 1, wc = wid & 1;
  const int row0 = blockIdx.y * 128, col0 = blockIdx.x * 128;
  const int lc = lane & 15, lg = lane >> 4;
  const int srow = lane >> 3, scol = (lane & 7) * 8;

  f32x4 acc[4][4];
#pragma unroll
  for (int m = 0; m < 4; m++)
#pragma unroll
    for (int n = 0; n < 4; n++) acc[m][n] = f32x4{0.f, 0.f, 0.f, 0.f};

  for (int k0 = 0; k0 < K; k0 += 64) {
#pragma unroll
    for (int i = 0; i < 4; i++) {
      const int chunk = wid * 4 + i;        // 0..15, wave-uniform
      const int r = chunk * 8 + srow;       // tile row 0..127
      stage16(A + (size_t)(row0 + r) * K + k0 + scol, sA + chunk * 512, lane);
      stage16(BT + (size_t)(col0 + r) * K + k0 + scol, sB + chunk * 512, lane);
    }
    asm volatile("s_waitcnt vmcnt(0)" ::: "memory");
    __syncthreads();
#pragma unroll
    for (int ks = 0; ks < 2; ks++) {
      bf16x8 af[4], bfr[4];
#pragma unroll
      for (int m = 0; m < 4; m++)
        af[m] = *reinterpret_cast<const bf16x8*>(sA + (wr * 64 + m * 16 + lc) * 64 + ks * 32 + lg * 8);
#pragma unroll
      for (int n = 0; n < 4; n++)
        bfr[n] = *reinterpret_cast<const bf16x8*>(sB + (wc * 64 + n * 16 + lc) * 64 + ks * 32 + lg * 8);
#pragma unroll
      for (int m = 0; m < 4; m++)
#pragma unroll
        for (int n = 0; n < 4; n++)
          acc[m][n] = __builtin_amdgcn_mfma_f32_16x16x32_bf16(af[m], bfr[n], acc[m][n], 0, 0, 0);
    }
    __syncthreads();
  }

  const int lr = lg * 4;
#pragma unroll
  for (int m = 0; m < 4; m++)
#pragma unroll
    for (int n = 0; n < 4; n++) {
      const int col = col0 + wc * 64 + n * 16 + lc;
      const float bv = bias[col];
#pragma unroll
      for (int r = 0; r < 4; r++) {
        const int row = row0 + wr * 64 + m * 16 + lr + r;
        const float v = acc[m][n][r] + bv;
        if constexpr (MODE == 0) {
          ((unsigned short*)out)[(size_t)row * N + col] = f2bf(v);
        } else if constexpr (MODE == 1) {
          const int b = row >> 11, t = row & 2047, h = col >> 7, d = col & 127;
          ((unsigned short*)out)[((size_t)(b * 16 + h) * 2048 + t) * 160 + d] = f2bf(v);
        } else if constexpr (MODE == 2) {
          const int b = row >> 11, t = row & 2047, h = col >> 7, d = col & 127;
          ((unsigned short*)out)[((size_t)(b * 16 + h) * 128 + d) * 2048 + t] = f2bf(v);
        } else {
          ((float*)out)[(size_t)row * N + col] = v;
        }
      }
    }
}

// ---------- RoPE: pre[row][512] fp32 -> Q/K buf [.., 128..159] bf16 ----------
__global__ void k_rope(const float* __restrict__ qpre, const float* __restrict__ kpre,
                       unsigned short* __restrict__ Qb, unsigned short* __restrict__ Kb) {
  const int idx = blockIdx.x * blockDim.x + threadIdx.x;  // 0 .. 2*1048576-1
  const int which = idx >> 20;
  const int e = idx & 1048575;
  const int i = e & 15, h = (e >> 4) & 15, row = e >> 8;
  const int t = row & 2047, b = row >> 11;
  const float* pre = which ? kpre : qpre;
  unsigned short* buf = which ? Kb : Qb;
  const float x1 = pre[(size_t)row * 512 + h * 32 + 2 * i];
  const float x2 = pre[(size_t)row * 512 + h * 32 + 2 * i + 1];
  const float f = exp2f(-(float)i * (13.287712379549449f / 16.f));  // 10000^(-i/16)
  const float th = (float)t * f;
  float sv, cv;
  sincosf(th, &sv, &cv);
  const size_t base = ((size_t)(b * 16 + h) * 2048 + t) * 160 + 128;
  buf[base + i] = f2bf(x1 * cv - x2 * sv);
  buf[base + 16 + i] = f2bf(x1 * sv + x2 * cv);
}

// ---------- Flash attention: 4 waves/block, 16 q-rows/wave, KVBLK=64 ----------
__global__ __launch_bounds__(256) void k_attn(const unsigned short* __restrict__ Qb,
                                              const unsigned short* __restrict__ Kb,
                                              const unsigned short* __restrict__ Vt,
                                              float* __restrict__ out) {
  __shared__ unsigned short P[2][4][16 * 64];
  const int lane = threadIdx.x & 63, wid = threadIdx.x >> 6;
  const int lc = lane & 15, lg = lane >> 4;
  const int bh = blockIdx.y;
  const int b = bh >> 4, h = bh & 15;
  const int q0 = blockIdx.x * 64 + wid * 16;

  const unsigned short* Qh = Qb + (size_t)bh * 2048 * 160;
  const unsigned short* Kh = Kb + (size_t)bh * 2048 * 160;
  const unsigned short* Vh = Vt + (size_t)bh * 128 * 2048;

  bf16x8 qf[5];
#pragma unroll
  for (int ks = 0; ks < 5; ks++)
    qf[ks] = *reinterpret_cast<const bf16x8*>(Qh + (size_t)(q0 + lc) * 160 + ks * 32 + lg * 8);

  f32x4 acc_o[8];
#pragma unroll
  for (int i = 0; i < 8; i++) acc_o[i] = f32x4{0.f, 0.f, 0.f, 0.f};
  float mrun[4] = {-1e30f, -1e30f, -1e30f, -1e30f};
  float lrun[4] = {0.f, 0.f, 0.f, 0.f};
  const float scale = 0.07905694150420949f;  // 1/sqrt(160)

  for (int it = 0; it < 32; it++) {
    const int kv0 = it * 64;
    f32x4 s[4];
#pragma unroll
    for (int kf = 0; kf < 4; kf++) s[kf] = f32x4{0.f, 0.f, 0.f, 0.f};
#pragma unroll
    for (int kf = 0; kf < 4; kf++)
#pragma unroll
      for (int ks = 0; ks < 5; ks++) {
        bf16x8 kfr = *reinterpret_cast<const bf16x8*>(Kh + (size_t)(kv0 + kf * 16 + lc) * 160 + ks * 32 + lg * 8);
        s[kf] = __builtin_amdgcn_mfma_f32_16x16x32_bf16(qf[ks], kfr, s[kf], 0, 0, 0);
      }

    const int pb = it & 1;
    unsigned short* Pw = P[pb][wid];
#pragma unroll
    for (int r = 0; r < 4; r++) {
      float s0 = s[0][r] * scale, s1 = s[1][r] * scale, s2 = s[2][r] * scale, s3 = s[3][r] * scale;
      float mx = fmaxf(fmaxf(s0, s1), fmaxf(s2, s3));
#pragma unroll
      for (int d = 8; d >= 1; d >>= 1) mx = fmaxf(mx, __shfl_xor(mx, d));
      const float mn = fmaxf(mrun[r], mx);
      const float corr = __expf(mrun[r] - mn);
      const float p0 = __expf(s0 - mn), p1 = __expf(s1 - mn), p2 = __expf(s2 - mn), p3 = __expf(s3 - mn);
      float rs = p0 + p1 + p2 + p3;
#pragma unroll
      for (int d = 8; d >= 1; d >>= 1) rs += __shfl_xor(rs, d);
      mrun[r] = mn;
      lrun[r] = lrun[r] * corr + rs;
#pragma unroll
      for (int df = 0; df < 8; df++) acc_o[df][r] *= corr;
      const int qrow = lg * 4 + r;
      Pw[qrow * 64 + lc] = f2bf(p0);
      Pw[qrow * 64 + 16 + lc] = f2bf(p1);
      Pw[qrow * 64 + 32 + lc] = f2bf(p2);
      Pw[qrow * 64 + 48 + lc] = f2bf(p3);
    }
    __syncthreads();
    const unsigned short* Pr = P[pb][wid];
    bf16x8 pa[2];
#pragma unroll
    for (int ks = 0; ks < 2; ks++)
      pa[ks] = *reinterpret_cast<const bf16x8*>(Pr + lc * 64 + ks * 32 + lg * 8);
#pragma unroll
    for (int df = 0; df < 8; df++)
#pragma unroll
      for (int ks = 0; ks < 2; ks++) {
        bf16x8 vf = *reinterpret_cast<const bf16x8*>(Vh + (size_t)(df * 16 + lc) * 2048 + kv0 + ks * 32 + lg * 8);
        acc_o[df] = __builtin_amdgcn_mfma_f32_16x16x32_bf16(pa[ks], vf, acc_o[df], 0, 0, 0);
      }
  }

#pragma unroll
  for (int df = 0; df < 8; df++) {
    const int d = h * 128 + df * 16 + lc;
#pragma unroll
    for (int r = 0; r < 4; r++) {
      const int q = q0 + lg * 4 + r;
      out[((size_t)b * 2048 + q) * 2048 + d] = acc_o[df][r] / lrun[r];
    }
  }
}

// ---------- launcher ----------
extern "C" void kernel_launch(void* const* d_in, const int* in_sizes, int n_in,
                              void* d_out, int out_size, void* d_ws, size_t ws_size,
                              hipStream_t stream) {
  (void)in_sizes; (void)n_in; (void)out_size;
  const float* x     = (const float*)d_in[0];
  const float* W_DKV = (const float*)d_in[1];
  const float* b_DKV = (const float*)d_in[2];
  const float* W_UK  = (const float*)d_in[3];
  const float* b_UK  = (const float*)d_in[4];
  const float* W_UV  = (const float*)d_in[5];
  const float* b_UV  = (const float*)d_in[6];
  const float* W_DQ  = (const float*)d_in[7];
  const float* b_DQ  = (const float*)d_in[8];
  const float* W_UQ  = (const float*)d_in[9];
  const float* b_UQ  = (const float*)d_in[10];
  const float* W_QR  = (const float*)d_in[11];
  const float* b_QR  = (const float*)d_in[12];
  const float* W_KR  = (const float*)d_in[13];
  const float* b_KR  = (const float*)d_in[14];
  float* out = (float*)d_out;

  char* ws = (char*)d_ws;
  // byte offsets (all 256B-aligned)
  unsigned short* xb    = (unsigned short*)(ws + 0);          // 4096x2048 bf16
  unsigned short* WTdkv = (unsigned short*)(ws + 16777216);   // [512][2048]
  unsigned short* WTuk  = (unsigned short*)(ws + 18874368);   // [2048][512]
  unsigned short* WTuv  = (unsigned short*)(ws + 20971520);   // [2048][512]
  unsigned short* WTdq  = (unsigned short*)(ws + 23068672);   // [512][2048]
  unsigned short* WTuq  = (unsigned short*)(ws + 25165824);   // [2048][512]
  unsigned short* WTqr  = (unsigned short*)(ws + 27262976);   // [512][512]
  unsigned short* WTkr  = (unsigned short*)(ws + 27787264);   // [512][2048]
  unsigned short* ckv   = (unsigned short*)(ws + 29884416);   // [4096][512]
  unsigned short* cq    = (unsigned short*)(ws + 34078720);   // [4096][512]
  unsigned short* Qbuf  = (unsigned short*)(ws + 38273024);   // (2,16,2048,160)
  unsigned short* Kbuf  = (unsigned short*)(ws + 59244544);   // (2,16,2048,160)
  unsigned short* Vtb   = (unsigned short*)(ws + 80216064);   // (2,16,128,2048)
  float*          qrp   = (float*)(ws + 96993280);            // [4096][512] fp32
  float*          krp   = (float*)(ws + 105381888);           // [4096][512] fp32
  if (ws_size < 113770496) return;  // loud failure rather than corruption

  const dim3 tb(32, 8);
  k_cvt_x<<<8192, 256, 0, stream>>>(x, xb, 8388608);
  k_tw<<<dim3(16, 64), tb, 0, stream>>>(W_DKV, WTdkv, 2048, 512);
  k_tw<<<dim3(64, 16), tb, 0, stream>>>(W_UK, WTuk, 512, 2048);
  k_tw<<<dim3(64, 16), tb, 0, stream>>>(W_UV, WTuv, 512, 2048);
  k_tw<<<dim3(16, 64), tb, 0, stream>>>(W_DQ, WTdq, 2048, 512);
  k_tw<<<dim3(64, 16), tb, 0, stream>>>(W_UQ, WTuq, 512, 2048);
  k_tw<<<dim3(16, 16), tb, 0, stream>>>(W_QR, WTqr, 512, 512);
  k_tw<<<dim3(16, 64), tb, 0, stream>>>(W_KR, WTkr, 2048, 512);

  // projections
  k_gemm<0><<<dim3(4, 32), 256, 0, stream>>>(xb, WTdkv, b_DKV, ckv, 512, 2048);
  k_gemm<0><<<dim3(4, 32), 256, 0, stream>>>(xb, WTdq, b_DQ, cq, 512, 2048);
  k_gemm<3><<<dim3(4, 32), 256, 0, stream>>>(xb, WTkr, b_KR, krp, 512, 2048);
  k_gemm<1><<<dim3(16, 32), 256, 0, stream>>>(ckv, WTuk, b_UK, Kbuf, 2048, 512);
  k_gemm<2><<<dim3(16, 32), 256, 0, stream>>>(ckv, WTuv, b_UV, Vtb, 2048, 512);
  k_gemm<1><<<dim3(16, 32), 256, 0, stream>>>(cq, WTuq, b_UQ, Qbuf, 2048, 512);
  k_gemm<3><<<dim3(4, 32), 256, 0, stream>>>(cq, WTqr, b_QR, qrp, 512, 512);

  k_rope<<<8192, 256, 0, stream>>>(qrp, krp, Qbuf, Kbuf);
  k_attn<<<dim3(32, 32), 256, 0, stream>>>(Qbuf, Kbuf, Vtb, out);
}

// Round 2
// 448.226 us; speedup vs baseline: 1.9387x; 1.9387x over previous
//
#include <hip/hip_runtime.h>
#include <hip/hip_bf16.h>
#include <cstdint>
#include <cstddef>

// ---------- types / helpers ----------
typedef __attribute__((ext_vector_type(8))) short  bf16x8;
typedef __attribute__((ext_vector_type(4))) float  f32x4;

#define DEVINL __device__ __forceinline__

#define ATT_SCALE 0.07905694150420949f  // 1/sqrt(160)

DEVINL unsigned short f2bf(float f) {
  unsigned int u = __float_as_uint(f);
  u += 0x7fff + ((u >> 16) & 1);   // round-to-nearest-even
  return (unsigned short)(u >> 16);
}

// global -> LDS staging: 16B per lane. lds_u must be wave-uniform; HW adds lane*16.
DEVINL void stage16(const unsigned short* __restrict__ g, unsigned short* lds_u, int lane) {
#if defined(__has_builtin) && __has_builtin(__builtin_amdgcn_global_load_lds)
  (void)lane;
  __builtin_amdgcn_global_load_lds((const __attribute__((address_space(1))) void*)g,
                                   (__attribute__((address_space(3))) void*)lds_u, 16, 0, 0);
#else
  bf16x8 v = *reinterpret_cast<const bf16x8*>(g);
  *reinterpret_cast<bf16x8*>(lds_u + (size_t)lane * 8) = v;
#endif
}

// ---------- elementwise conversions ----------
__global__ void k_cvt_x(const float* __restrict__ x, unsigned short* __restrict__ o, int n) {
  int i = (blockIdx.x * blockDim.x + threadIdx.x) * 4;
  if (i >= n) return;
  float4 v = *reinterpret_cast<const float4*>(x + i);
  ushort4 r;
  r.x = f2bf(v.x); r.y = f2bf(v.y); r.z = f2bf(v.z); r.w = f2bf(v.w);
  *reinterpret_cast<ushort4*>(o + i) = r;
}

// W[K][N] fp32 -> WT[N][K] bf16 (tiled transpose)
__global__ void k_tw(const float* __restrict__ W, unsigned short* __restrict__ WT, int K, int N) {
  __shared__ float t[32][33];
  int n0 = blockIdx.x * 32, k0 = blockIdx.y * 32;
  int tx = threadIdx.x, ty = threadIdx.y;  // (32,8)
#pragma unroll
  for (int j = 0; j < 4; j++)
    t[ty + j * 8][tx] = W[(size_t)(k0 + ty + j * 8) * N + n0 + tx];
  __syncthreads();
#pragma unroll
  for (int j = 0; j < 4; j++)
    WT[(size_t)(n0 + ty + j * 8) * K + k0 + tx] = f2bf(t[tx][ty + j * 8]);
}

// ---------- fragment-linear K/V scatter offsets ----------
// K tile layout: per (b,h,it): 20 frags (ks*4+kf) of 512 shorts; lane off = lg*128+lc*8+e
DEVINL size_t koff(int b, int h, int t, int d) {
  const int it = t >> 6, kf = (t >> 4) & 3, lc = t & 15;
  const int ks = d >> 5, lg = (d >> 3) & 3, e = d & 7;
  return ((size_t)(b * 16 + h) * 32 + it) * 10240 + (size_t)(ks * 4 + kf) * 512 + lg * 128 + lc * 8 + e;
}
// V tile layout: per (b,h,it): 16 frags (ks2*8+df) of 512 shorts
DEVINL size_t voff(int b, int h, int t, int dv) {
  const int it = t >> 6, ks2 = (t >> 5) & 1, lg = (t >> 3) & 3, e = t & 7;
  const int df = dv >> 4, lc = dv & 15;
  return ((size_t)(b * 16 + h) * 32 + it) * 8192 + (size_t)(ks2 * 8 + df) * 512 + lg * 128 + lc * 8 + e;
}

// ---------- GEMM: C[M][cols] = A[M][K](bf16) * WT[cols][K](bf16) + bias, fused epilogues ----------
// MODE 10: x -> [ckv(bf16) | cq(bf16) | krp(f32)], segments of 512 cols
// MODE 11: ckv -> [Kfrag(2048) | Vfrag(2048)]
// MODE 12: cq  -> [Q row-major*scale (2048) | qrp f32 (512)]
template <int MODE>
__global__ __launch_bounds__(256) void k_gemm(const unsigned short* __restrict__ A,
                                              const unsigned short* __restrict__ BT,
                                              const float* __restrict__ bias0,
                                              const float* __restrict__ bias1,
                                              const float* __restrict__ bias2,
                                              void* __restrict__ o0, void* __restrict__ o1,
                                              void* __restrict__ o2, int K) {
  __shared__ unsigned short sA[128 * 64];
  __shared__ unsigned short sB[128 * 64];
  const int tid = threadIdx.x;
  const int lane = tid & 63, wid = tid >> 6;
  const int wr = wid >> 1, wc = wid & 1;
  const int row0 = blockIdx.y * 128, col0 = blockIdx.x * 128;
  const int lc = lane & 15, lg = lane >> 4;
  const int srow = lane >> 3, scol = (lane & 7) * 8;

  f32x4 acc[4][4];
#pragma unroll
  for (int m = 0; m < 4; m++)
#pragma unroll
    for (int n = 0; n < 4; n++) acc[m][n] = f32x4{0.f, 0.f, 0.f, 0.f};

  for (int k0 = 0; k0 < K; k0 += 64) {
#pragma unroll
    for (int i = 0; i < 4; i++) {
      const int chunk = wid * 4 + i;        // 0..15, wave-uniform
      const int r = chunk * 8 + srow;       // tile row 0..127
      stage16(A + (size_t)(row0 + r) * K + k0 + scol, sA + chunk * 512, lane);
      stage16(BT + (size_t)(col0 + r) * K + k0 + scol, sB + chunk * 512, lane);
    }
    asm volatile("s_waitcnt vmcnt(0)" ::: "memory");
    __syncthreads();
#pragma unroll
    for (int ks = 0; ks < 2; ks++) {
      bf16x8 af[4], bfr[4];
#pragma unroll
      for (int m = 0; m < 4; m++)
        af[m] = *reinterpret_cast<const bf16x8*>(sA + (wr * 64 + m * 16 + lc) * 64 + ks * 32 + lg * 8);
#pragma unroll
      for (int n = 0; n < 4; n++)
        bfr[n] = *reinterpret_cast<const bf16x8*>(sB + (wc * 64 + n * 16 + lc) * 64 + ks * 32 + lg * 8);
#pragma unroll
      for (int m = 0; m < 4; m++)
#pragma unroll
        for (int n = 0; n < 4; n++)
          acc[m][n] = __builtin_amdgcn_mfma_f32_16x16x32_bf16(af[m], bfr[n], acc[m][n], 0, 0, 0);
    }
    __syncthreads();
  }

  const int lr = lg * 4;
#pragma unroll
  for (int m = 0; m < 4; m++)
#pragma unroll
    for (int n = 0; n < 4; n++) {
      const int col = col0 + wc * 64 + n * 16 + lc;
      float bv;
      if constexpr (MODE == 10)
        bv = (col < 512) ? bias0[col] : (col < 1024) ? bias1[col - 512] : bias2[col - 1024];
      else
        bv = (col < 2048) ? bias0[col] : bias1[col - 2048];
#pragma unroll
      for (int r = 0; r < 4; r++) {
        const int row = row0 + wr * 64 + m * 16 + lr + r;
        const float v = acc[m][n][r] + bv;
        const int b = row >> 11, t = row & 2047;
        if constexpr (MODE == 10) {
          if (col < 512)        ((unsigned short*)o0)[(size_t)row * 512 + col] = f2bf(v);
          else if (col < 1024)  ((unsigned short*)o1)[(size_t)row * 512 + col - 512] = f2bf(v);
          else                  ((float*)o2)[(size_t)row * 512 + col - 1024] = v;
        } else if constexpr (MODE == 11) {
          if (col < 2048) {
            const int h = col >> 7, d = col & 127;
            ((unsigned short*)o0)[koff(b, h, t, d)] = f2bf(v);
          } else {
            const int c = col - 2048, h = c >> 7, dv = c & 127;
            ((unsigned short*)o1)[voff(b, h, t, dv)] = f2bf(v);
          }
        } else {  // MODE 12
          if (col < 2048) {
            const int h = col >> 7, d = col & 127;
            ((unsigned short*)o0)[((size_t)(b * 16 + h) * 2048 + t) * 160 + d] = f2bf(v * ATT_SCALE);
          } else {
            ((float*)o1)[(size_t)row * 512 + col - 2048] = v;
          }
        }
      }
    }
}

// ---------- RoPE: pre[row][512] fp32 -> Q(row-major, scaled) / K(frag layout) ----------
__global__ void k_rope(const float* __restrict__ qpre, const float* __restrict__ kpre,
                       unsigned short* __restrict__ Qb, unsigned short* __restrict__ Kf) {
  const int idx = blockIdx.x * blockDim.x + threadIdx.x;  // 0 .. 2*1048576-1
  const int which = idx >> 20;
  const int e = idx & 1048575;
  const int i = e & 15, h = (e >> 4) & 15, row = e >> 8;
  const int t = row & 2047, b = row >> 11;
  const float* pre = which ? kpre : qpre;
  const float x1 = pre[(size_t)row * 512 + h * 32 + 2 * i];
  const float x2 = pre[(size_t)row * 512 + h * 32 + 2 * i + 1];
  const float f = exp2f(-(float)i * (13.287712379549449f / 16.f));  // 10000^(-i/16)
  const float th = (float)t * f;
  float sv, cv;
  sincosf(th, &sv, &cv);
  const float o1 = x1 * cv - x2 * sv, o2 = x1 * sv + x2 * cv;
  if (which == 0) {
    const size_t base = ((size_t)(b * 16 + h) * 2048 + t) * 160 + 128;
    Qb[base + i]      = f2bf(o1 * ATT_SCALE);
    Qb[base + 16 + i] = f2bf(o2 * ATT_SCALE);
  } else {
    Kf[koff(b, h, t, 128 + i)] = f2bf(o1);
    Kf[koff(b, h, t, 144 + i)] = f2bf(o2);
  }
}

// ---------- Flash attention: frag-linear K (LDS dbuf) + frag-linear V (reg prefetch) ----------
__global__ __launch_bounds__(256, 2) void k_attn(const unsigned short* __restrict__ Qb,
                                                 const unsigned short* __restrict__ Kf,
                                                 const unsigned short* __restrict__ Vf,
                                                 float* __restrict__ out) {
  __shared__ unsigned short sK[2][10240];   // 20KB x2, frag-linear
  __shared__ unsigned short sP[4][16 * 72]; // stride 72 shorts: conflict-free both sides
  const int lane = threadIdx.x & 63, wid = threadIdx.x >> 6;
  const int lc = lane & 15, lg = lane >> 4;

  // XCD swizzle: each XCD owns 4 consecutive heads (L2 working set ~4.5MB)
  const int L = blockIdx.x;
  const int xcd = L & 7, w = L >> 3;
  const int bh = xcd * 4 + (w & 3);
  const int qblk = w >> 2;
  const int b = bh >> 4, h = bh & 15;
  const int q0 = qblk * 64 + wid * 16;

  const unsigned short* Qh = Qb + (size_t)bh * 2048 * 160;
  const unsigned short* Kh = Kf + (size_t)bh * 32 * 10240;
  const unsigned short* Vh = Vf + (size_t)bh * 32 * 8192;

  // prologue: stage K tile 0
#pragma unroll
  for (int i = 0; i < 5; i++) {
    const int chunk = wid * 5 + i;
    stage16(Kh + (size_t)chunk * 512 + lane * 8, &sK[0][0] + chunk * 512, lane);
  }

  bf16x8 qf[5];
#pragma unroll
  for (int ks = 0; ks < 5; ks++)
    qf[ks] = *reinterpret_cast<const bf16x8*>(Qh + (size_t)(q0 + lc) * 160 + ks * 32 + lg * 8);

  f32x4 acc_o[8];
#pragma unroll
  for (int i = 0; i < 8; i++) acc_o[i] = f32x4{0.f, 0.f, 0.f, 0.f};
  float mrun[4] = {-1e30f, -1e30f, -1e30f, -1e30f};
  float lrun[4] = {0.f, 0.f, 0.f, 0.f};

  __syncthreads();

  int buf = 0;
  for (int it = 0; it < 32; it++) {
    // stage next K tile into the other buffer (in flight across whole iteration)
    if (it < 31) {
      const unsigned short* src = Kh + (size_t)(it + 1) * 10240;
      unsigned short* dst = &sK[buf ^ 1][0];
#pragma unroll
      for (int i = 0; i < 5; i++) {
        const int chunk = wid * 5 + i;
        stage16(src + (size_t)chunk * 512 + lane * 8, dst + chunk * 512, lane);
      }
    }
    // V tile -> regs (coalesced 1KB loads, L2-hot; in flight during QK+softmax)
    bf16x8 vf[16];
    {
      const unsigned short* Vt = Vh + (size_t)it * 8192;
#pragma unroll
      for (int g = 0; g < 16; g++)
        vf[g] = *reinterpret_cast<const bf16x8*>(Vt + g * 512 + lane * 8);
    }
    // QK^T from LDS (lane-contiguous ds_read_b128, conflict-free)
    f32x4 s[4];
#pragma unroll
    for (int kf = 0; kf < 4; kf++) s[kf] = f32x4{0.f, 0.f, 0.f, 0.f};
    const unsigned short* sKb = &sK[buf][0];
#pragma unroll
    for (int ks = 0; ks < 5; ks++)
#pragma unroll
      for (int kf = 0; kf < 4; kf++) {
        bf16x8 kfr = *reinterpret_cast<const bf16x8*>(sKb + (ks * 4 + kf) * 512 + lane * 8);
        s[kf] = __builtin_amdgcn_mfma_f32_16x16x32_bf16(qf[ks], kfr, s[kf], 0, 0, 0);
      }
    // online softmax (scale pre-folded into Q)
    unsigned short* Pw = &sP[wid][0];
#pragma unroll
    for (int r = 0; r < 4; r++) {
      float s0 = s[0][r], s1 = s[1][r], s2 = s[2][r], s3 = s[3][r];
      float mx = fmaxf(fmaxf(s0, s1), fmaxf(s2, s3));
#pragma unroll
      for (int d = 8; d >= 1; d >>= 1) mx = fmaxf(mx, __shfl_xor(mx, d));
      const float mn = fmaxf(mrun[r], mx);
      const float corr = __expf(mrun[r] - mn);
      const float p0 = __expf(s0 - mn), p1 = __expf(s1 - mn), p2 = __expf(s2 - mn), p3 = __expf(s3 - mn);
      float rs = p0 + p1 + p2 + p3;
#pragma unroll
      for (int d = 8; d >= 1; d >>= 1) rs += __shfl_xor(rs, d);
      mrun[r] = mn;
      lrun[r] = lrun[r] * corr + rs;
#pragma unroll
      for (int df = 0; df < 8; df++) acc_o[df][r] *= corr;
      const int qrow = lg * 4 + r;
      Pw[qrow * 72 + lc]      = f2bf(p0);
      Pw[qrow * 72 + 16 + lc] = f2bf(p1);
      Pw[qrow * 72 + 32 + lc] = f2bf(p2);
      Pw[qrow * 72 + 48 + lc] = f2bf(p3);
    }
    // P (C-layout) -> A-layout via per-wave LDS
    bf16x8 pa[2];
#pragma unroll
    for (int k = 0; k < 2; k++)
      pa[k] = *reinterpret_cast<const bf16x8*>(&sP[wid][0] + lc * 72 + k * 32 + lg * 8);
    // PV
#pragma unroll
    for (int k = 0; k < 2; k++)
#pragma unroll
      for (int df = 0; df < 8; df++)
        acc_o[df] = __builtin_amdgcn_mfma_f32_16x16x32_bf16(pa[k], vf[k * 8 + df], acc_o[df], 0, 0, 0);

    __syncthreads();  // staging of buf^1 done; all waves done reading buf
    buf ^= 1;
  }

#pragma unroll
  for (int df = 0; df < 8; df++) {
    const int d = h * 128 + df * 16 + lc;
#pragma unroll
    for (int r = 0; r < 4; r++) {
      const int q = q0 + lg * 4 + r;
      out[((size_t)b * 2048 + q) * 2048 + d] = acc_o[df][r] / lrun[r];
    }
  }
}

// ---------- launcher ----------
extern "C" void kernel_launch(void* const* d_in, const int* in_sizes, int n_in,
                              void* d_out, int out_size, void* d_ws, size_t ws_size,
                              hipStream_t stream) {
  (void)in_sizes; (void)n_in; (void)out_size;
  const float* x     = (const float*)d_in[0];
  const float* W_DKV = (const float*)d_in[1];
  const float* b_DKV = (const float*)d_in[2];
  const float* W_UK  = (const float*)d_in[3];
  const float* b_UK  = (const float*)d_in[4];
  const float* W_UV  = (const float*)d_in[5];
  const float* b_UV  = (const float*)d_in[6];
  const float* W_DQ  = (const float*)d_in[7];
  const float* b_DQ  = (const float*)d_in[8];
  const float* W_UQ  = (const float*)d_in[9];
  const float* b_UQ  = (const float*)d_in[10];
  const float* W_QR  = (const float*)d_in[11];
  const float* b_QR  = (const float*)d_in[12];
  const float* W_KR  = (const float*)d_in[13];
  const float* b_KR  = (const float*)d_in[14];
  float* out = (float*)d_out;

  char* ws = (char*)d_ws;
  unsigned short* xb     = (unsigned short*)(ws + 0);          // [4096][2048] bf16
  unsigned short* WTcat1 = (unsigned short*)(ws + 16777216);   // [1536][2048] (dkv|dq|kr)
  unsigned short* WTcat2 = (unsigned short*)(ws + 23068672);   // [4096][512]  (uk|uv)
  unsigned short* WTcat3 = (unsigned short*)(ws + 27262976);   // [2560][512]  (uq|qr)
  unsigned short* ckv    = (unsigned short*)(ws + 29884416);   // [4096][512]
  unsigned short* cq     = (unsigned short*)(ws + 34078720);   // [4096][512]
  unsigned short* Qbuf   = (unsigned short*)(ws + 38273024);   // (2,16,2048,160) row-major, pre-scaled
  unsigned short* Kfb    = (unsigned short*)(ws + 59244544);   // frag-linear K
  unsigned short* Vfb    = (unsigned short*)(ws + 80216064);   // frag-linear V
  float*          qrp    = (float*)(ws + 96993280);            // [4096][512] fp32
  float*          krp    = (float*)(ws + 105381888);           // [4096][512] fp32
  if (ws_size < 113770496) return;

  const dim3 tb(32, 8);
  k_cvt_x<<<8192, 256, 0, stream>>>(x, xb, 8388608);
  k_tw<<<dim3(16, 64), tb, 0, stream>>>(W_DKV, WTcat1, 2048, 512);
  k_tw<<<dim3(16, 64), tb, 0, stream>>>(W_DQ,  WTcat1 + (size_t)512 * 2048, 2048, 512);
  k_tw<<<dim3(16, 64), tb, 0, stream>>>(W_KR,  WTcat1 + (size_t)1024 * 2048, 2048, 512);
  k_tw<<<dim3(64, 16), tb, 0, stream>>>(W_UK,  WTcat2, 512, 2048);
  k_tw<<<dim3(64, 16), tb, 0, stream>>>(W_UV,  WTcat2 + (size_t)2048 * 512, 512, 2048);
  k_tw<<<dim3(64, 16), tb, 0, stream>>>(W_UQ,  WTcat3, 512, 2048);
  k_tw<<<dim3(16, 16), tb, 0, stream>>>(W_QR,  WTcat3 + (size_t)2048 * 512, 512, 512);

  // stage 1: x @ [W_DKV | W_DQ | W_KR]
  k_gemm<10><<<dim3(12, 32), 256, 0, stream>>>(xb, WTcat1, b_DKV, b_DQ, b_KR,
                                               ckv, cq, krp, 2048);
  // stage 2: ckv @ [W_UK | W_UV] -> frag K/V ; cq @ [W_UQ | W_QR] -> Q(scaled)/qrp
  k_gemm<11><<<dim3(32, 32), 256, 0, stream>>>(ckv, WTcat2, b_UK, b_UV, nullptr,
                                               Kfb, Vfb, nullptr, 512);
  k_gemm<12><<<dim3(20, 32), 256, 0, stream>>>(cq, WTcat3, b_UQ, b_QR, nullptr,
                                               Qbuf, qrp, nullptr, 512);

  k_rope<<<8192, 256, 0, stream>>>(qrp, krp, Qbuf, Kfb);
  k_attn<<<1024, 256, 0, stream>>>(Qbuf, Kfb, Vfb, out);
}

// Round 4
// 354.312 us; speedup vs baseline: 2.4526x; 1.2651x over previous
//
#include <hip/hip_runtime.h>
#include <hip/hip_bf16.h>
#include <cstdint>
#include <cstddef>

// ---------- types / helpers ----------
typedef __attribute__((ext_vector_type(8)))  short bf16x8;
typedef __attribute__((ext_vector_type(4)))  float f32x4;
typedef __attribute__((ext_vector_type(16))) float f32x16;
typedef __attribute__((ext_vector_type(4)))  int   i32x4;

#define DEVINL __device__ __forceinline__

#define ATT_SCALE 0.07905694150420949f                    // 1/sqrt(160)
#define QSCALE    (0.07905694150420949f * 1.4426950408889634f)  // fold log2(e): softmax in exp2 domain

DEVINL unsigned short f2bf(float f) {
  unsigned int u = __float_as_uint(f);
  u += 0x7fff + ((u >> 16) & 1);   // round-to-nearest-even
  return (unsigned short)(u >> 16);
}

DEVINL int cvtpk(float lo, float hi) {   // word = (bf16(lo), bf16(hi))
  int r;
  asm("v_cvt_pk_bf16_f32 %0, %1, %2" : "=v"(r) : "v"(lo), "v"(hi));
  return r;
}

// global -> LDS staging: 16B per lane. lds_u must be wave-uniform; HW adds lane*16.
DEVINL void stage16(const unsigned short* __restrict__ g, unsigned short* lds_u, int lane) {
  (void)lane;
  __builtin_amdgcn_global_load_lds((const __attribute__((address_space(1))) void*)g,
                                   (__attribute__((address_space(3))) void*)lds_u, 16, 0, 0);
}

// ---------- elementwise conversions ----------
__global__ void k_cvt_x(const float* __restrict__ x, unsigned short* __restrict__ o, int n) {
  int i = (blockIdx.x * blockDim.x + threadIdx.x) * 4;
  if (i >= n) return;
  float4 v = *reinterpret_cast<const float4*>(x + i);
  ushort4 r;
  r.x = f2bf(v.x); r.y = f2bf(v.y); r.z = f2bf(v.z); r.w = f2bf(v.w);
  *reinterpret_cast<ushort4*>(o + i) = r;
}

// All 7 weight transposes in one launch. W[K][N] fp32 -> WT[N][K] bf16.
struct TwArgs { const float* W[7]; unsigned short* D[7]; };
__global__ void k_tw_all(TwArgs a) {
  __shared__ float t[32][33];
  const int bid = blockIdx.x;
  int w, K, N, bx, by;
  if (bid < 3072)      { w = bid >> 10; int r = bid & 1023; K = 2048; N = 512;  bx = r & 15; by = r >> 4; }
  else if (bid < 6144) { int r = bid - 3072; w = 3 + (r >> 10); r &= 1023; K = 512; N = 2048; bx = r & 63; by = r >> 6; }
  else                 { int r = bid - 6144; w = 6; K = 512; N = 512; bx = r & 15; by = r >> 4; }
  const float* W = a.W[w];
  unsigned short* D = a.D[w];
  const int n0 = bx * 32, k0 = by * 32;
  const int tx = threadIdx.x, ty = threadIdx.y;  // (32,8)
#pragma unroll
  for (int j = 0; j < 4; j++)
    t[ty + j * 8][tx] = W[(size_t)(k0 + ty + j * 8) * N + n0 + tx];
  __syncthreads();
#pragma unroll
  for (int j = 0; j < 4; j++)
    D[(size_t)(n0 + ty + j * 8) * K + k0 + tx] = f2bf(t[tx][ty + j * 8]);
}

// ---------- fragment-linear K/V scatter offsets (32x32x16 MFMA operand layout) ----------
// K per (b,h,it): 20 frags (kvt*10+ks) of 512 shorts; lane l gets K[kv=kvt*32+(l&31)][d=ks*16+(l>>5)*8+e]
DEVINL size_t koff(int bh, int t, int d) {
  const int it = t >> 6, t6 = t & 63;
  const int kvt = t6 >> 5, lanelo = t6 & 31;
  const int ks = d >> 4, hi = (d >> 3) & 1, e = d & 7;
  return ((size_t)bh * 32 + it) * 10240 + (size_t)(kvt * 10 + ks) * 512 + (hi * 32 + lanelo) * 8 + e;
}
// V per (b,h,it): 16 frags (dvt*4+ks) of 512 shorts; lane l gets V[kv=ks*16+(l>>5)*8+e][dv=dvt*32+(l&31)]
DEVINL size_t voff(int bh, int t, int dv) {
  const int it = t >> 6, t6 = t & 63;
  const int ks = t6 >> 4, hi = (t6 >> 3) & 1, e = t6 & 7;
  const int dvt = dv >> 5, lanelo = dv & 31;
  return ((size_t)bh * 32 + it) * 8192 + (size_t)(dvt * 4 + ks) * 512 + (hi * 32 + lanelo) * 8 + e;
}

// ---------- GEMM: C[M][cols] = A[M][K](bf16) * WT[cols][K](bf16) + bias, fused epilogues ----------
// MODE 10: x -> [ckv(bf16) | cq(bf16) | krp(f32)], segments of 512 cols
// MODE 11: ckv -> [Kfrag(2048) | Vfrag(2048)]
// MODE 12: cq  -> [Q row-major * QSCALE (2048) | qrp f32 (512)]
template <int MODE>
__global__ __launch_bounds__(256) void k_gemm(const unsigned short* __restrict__ A,
                                              const unsigned short* __restrict__ BT,
                                              const float* __restrict__ bias0,
                                              const float* __restrict__ bias1,
                                              const float* __restrict__ bias2,
                                              void* __restrict__ o0, void* __restrict__ o1,
                                              void* __restrict__ o2, int K) {
  __shared__ unsigned short sA[128 * 64];
  __shared__ unsigned short sB[128 * 64];
  const int tid = threadIdx.x;
  const int lane = tid & 63, wid = tid >> 6;
  const int wr = wid >> 1, wc = wid & 1;
  const int row0 = blockIdx.y * 128, col0 = blockIdx.x * 128;
  const int lc = lane & 15, lg = lane >> 4;
  const int srow = lane >> 3, scol = (lane & 7) * 8;

  f32x4 acc[4][4];
#pragma unroll
  for (int m = 0; m < 4; m++)
#pragma unroll
    for (int n = 0; n < 4; n++) acc[m][n] = f32x4{0.f, 0.f, 0.f, 0.f};

  for (int k0 = 0; k0 < K; k0 += 64) {
#pragma unroll
    for (int i = 0; i < 4; i++) {
      const int chunk = wid * 4 + i;        // 0..15, wave-uniform
      const int r = chunk * 8 + srow;       // tile row 0..127
      stage16(A + (size_t)(row0 + r) * K + k0 + scol, sA + chunk * 512, lane);
      stage16(BT + (size_t)(col0 + r) * K + k0 + scol, sB + chunk * 512, lane);
    }
    asm volatile("s_waitcnt vmcnt(0)" ::: "memory");
    __syncthreads();
#pragma unroll
    for (int ks = 0; ks < 2; ks++) {
      bf16x8 af[4], bfr[4];
#pragma unroll
      for (int m = 0; m < 4; m++)
        af[m] = *reinterpret_cast<const bf16x8*>(sA + (wr * 64 + m * 16 + lc) * 64 + ks * 32 + lg * 8);
#pragma unroll
      for (int n = 0; n < 4; n++)
        bfr[n] = *reinterpret_cast<const bf16x8*>(sB + (wc * 64 + n * 16 + lc) * 64 + ks * 32 + lg * 8);
#pragma unroll
      for (int m = 0; m < 4; m++)
#pragma unroll
        for (int n = 0; n < 4; n++)
          acc[m][n] = __builtin_amdgcn_mfma_f32_16x16x32_bf16(af[m], bfr[n], acc[m][n], 0, 0, 0);
    }
    __syncthreads();
  }

  const int lr = lg * 4;
#pragma unroll
  for (int m = 0; m < 4; m++)
#pragma unroll
    for (int n = 0; n < 4; n++) {
      const int col = col0 + wc * 64 + n * 16 + lc;
      float bv;
      if constexpr (MODE == 10)
        bv = (col < 512) ? bias0[col] : (col < 1024) ? bias1[col - 512] : bias2[col - 1024];
      else
        bv = (col < 2048) ? bias0[col] : bias1[col - 2048];
#pragma unroll
      for (int r = 0; r < 4; r++) {
        const int row = row0 + wr * 64 + m * 16 + lr + r;
        const float v = acc[m][n][r] + bv;
        const int b = row >> 11, t = row & 2047;
        if constexpr (MODE == 10) {
          if (col < 512)        ((unsigned short*)o0)[(size_t)row * 512 + col] = f2bf(v);
          else if (col < 1024)  ((unsigned short*)o1)[(size_t)row * 512 + col - 512] = f2bf(v);
          else                  ((float*)o2)[(size_t)row * 512 + col - 1024] = v;
        } else if constexpr (MODE == 11) {
          if (col < 2048) {
            const int h = col >> 7, d = col & 127;
            ((unsigned short*)o0)[koff(b * 16 + h, t, d)] = f2bf(v);
          } else {
            const int c = col - 2048, h = c >> 7, dv = c & 127;
            ((unsigned short*)o1)[voff(b * 16 + h, t, dv)] = f2bf(v);
          }
        } else {  // MODE 12
          if (col < 2048) {
            const int h = col >> 7, d = col & 127;
            ((unsigned short*)o0)[((size_t)(b * 16 + h) * 2048 + t) * 160 + d] = f2bf(v * QSCALE);
          } else {
            ((float*)o1)[(size_t)row * 512 + col - 2048] = v;
          }
        }
      }
    }
}

// ---------- RoPE: pre[row][512] fp32 -> Q(row-major, QSCALE) / K(frag layout) ----------
__global__ void k_rope(const float* __restrict__ qpre, const float* __restrict__ kpre,
                       unsigned short* __restrict__ Qb, unsigned short* __restrict__ Kf) {
  const int idx = blockIdx.x * blockDim.x + threadIdx.x;  // 0 .. 2*1048576-1
  const int which = idx >> 20;
  const int e = idx & 1048575;
  const int i = e & 15, h = (e >> 4) & 15, row = e >> 8;
  const int t = row & 2047, b = row >> 11;
  const float* pre = which ? kpre : qpre;
  const float x1 = pre[(size_t)row * 512 + h * 32 + 2 * i];
  const float x2 = pre[(size_t)row * 512 + h * 32 + 2 * i + 1];
  const float f = exp2f(-(float)i * (13.287712379549449f / 16.f));  // 10000^(-i/16)
  const float th = (float)t * f;
  float sv, cv;
  sincosf(th, &sv, &cv);
  const float o1 = x1 * cv - x2 * sv, o2 = x1 * sv + x2 * cv;
  if (which == 0) {
    const size_t base = ((size_t)(b * 16 + h) * 2048 + t) * 160 + 128;
    Qb[base + i]      = f2bf(o1 * QSCALE);
    Qb[base + 16 + i] = f2bf(o2 * QSCALE);
  } else {
    Kf[koff(b * 16 + h, t, 128 + i)] = f2bf(o1);
    Kf[koff(b * 16 + h, t, 144 + i)] = f2bf(o2);
  }
}

// ---------- Flash attention, m214-style: 32x32x16 MFMA, swapped QK & PV, in-register softmax ----------
// 4 waves x 32 q-rows = 128 q/block. Lane l: q = l&31 (hi = l>>5 duplicates stats).
// S' = K.Q^T  -> lane holds S[kv=crow(r,hi)+32*kvt][q=l&31]   (crow = (r&3)+8*(r>>2)+4*hi)
// O' = V^T.P^T -> lane holds O[dv=crow(r,hi)+32*dvt][q=l&31]  -> rescale/div lane-local
__global__ __launch_bounds__(256, 2) void k_attn(const unsigned short* __restrict__ Qb,
                                                 const unsigned short* __restrict__ Kf,
                                                 const unsigned short* __restrict__ Vf,
                                                 float* __restrict__ out) {
  __shared__ unsigned short sK[2][10240];   // 20KB x2 frag-linear K; reused as fp32 O-transpose at end
  const int lane = threadIdx.x & 63, wid = threadIdx.x >> 6;
  const int lanelo = lane & 31, hi = lane >> 5;

  // XCD swizzle: each XCD owns 4 consecutive heads
  const int L = blockIdx.x;
  const int xcd = L & 7, w = L >> 3;
  const int bh = xcd * 4 + (w & 3);
  const int qblk = w >> 2;
  const int b = bh >> 4, h = bh & 15;
  const int q0 = qblk * 128 + wid * 32;

  const unsigned short* Qh = Qb + (size_t)bh * 2048 * 160;
  const unsigned short* Kh = Kf + (size_t)bh * 32 * 10240;
  const unsigned short* Vh = Vf + (size_t)bh * 32 * 8192;

  // Q fragments (B-operand of swapped QK): lane l holds Q[q0+lanelo][ks*16+hi*8 .. +7]
  bf16x8 qf[10];
#pragma unroll
  for (int ks = 0; ks < 10; ks++)
    qf[ks] = *reinterpret_cast<const bf16x8*>(Qh + (size_t)(q0 + lanelo) * 160 + ks * 16 + hi * 8);

  // prologue: stage K tile 0 (20 chunks / 4 waves)
#pragma unroll
  for (int i = 0; i < 5; i++) {
    const int chunk = wid * 5 + i;
    stage16(Kh + (size_t)chunk * 512 + lane * 8, &sK[0][0] + chunk * 512, lane);
  }

  f32x16 o[4] = {};             // O^T accum: 4 dv-tiles x 16 regs
  float mrun = -1e30f, lrun = 0.f;

  asm volatile("s_waitcnt vmcnt(0)" ::: "memory");
  __syncthreads();

  int buf = 0;
  for (int it = 0; it < 32; it++) {
    // stage next K tile
    if (it < 31) {
      const unsigned short* src = Kh + (size_t)(it + 1) * 10240;
      unsigned short* dst = &sK[buf ^ 1][0];
#pragma unroll
      for (int i = 0; i < 5; i++) {
        const int chunk = wid * 5 + i;
        stage16(src + (size_t)chunk * 512 + lane * 8, dst + chunk * 512, lane);
      }
    }
    const unsigned short* Vt = Vh + (size_t)it * 8192;
    // V frags, first half (dvt 0,1)
    bf16x8 va[8];
#pragma unroll
    for (int f = 0; f < 8; f++)
      va[f] = *reinterpret_cast<const bf16x8*>(Vt + f * 512 + lane * 8);

    // QK^T (swapped): A=K frag from LDS, B=Q frag
    f32x16 s0 = {}, s1 = {};
    const unsigned short* sKb = &sK[buf][0];
#pragma unroll
    for (int ks = 0; ks < 10; ks++) {
      bf16x8 kf0 = *reinterpret_cast<const bf16x8*>(sKb + (size_t)ks * 512 + lane * 8);
      s0 = __builtin_amdgcn_mfma_f32_32x32x16_bf16(kf0, qf[ks], s0, 0, 0, 0);
      bf16x8 kf1 = *reinterpret_cast<const bf16x8*>(sKb + (size_t)(10 + ks) * 512 + lane * 8);
      s1 = __builtin_amdgcn_mfma_f32_32x32x16_bf16(kf1, qf[ks], s1, 0, 0, 0);
    }
    // V frags, second half (dvt 2,3) — in flight during softmax
    bf16x8 vb[8];
#pragma unroll
    for (int f = 0; f < 8; f++)
      vb[f] = *reinterpret_cast<const bf16x8*>(Vt + (size_t)(8 + f) * 512 + lane * 8);

    // ---- in-register online softmax (exp2 domain; scale pre-folded into Q) ----
    float mx = s0[0];
#pragma unroll
    for (int r = 1; r < 16; r++) mx = fmaxf(mx, s0[r]);
#pragma unroll
    for (int r = 0; r < 16; r++) mx = fmaxf(mx, s1[r]);
    mx = fmaxf(mx, __shfl_xor(mx, 32));

    if (__any(mx > mrun + 8.f)) {          // defer-max: rescale only on real growth
      const float mn = fmaxf(mrun, mx);
      const float corr = exp2f(mrun - mn); // ==1 for non-growing lanes
      lrun *= corr;
#pragma unroll
      for (int d = 0; d < 4; d++)
#pragma unroll
        for (int r = 0; r < 16; r++) o[d][r] *= corr;
      mrun = mn;
    }

    float pe0[16], pe1[16];
    float rs = 0.f;
#pragma unroll
    for (int r = 0; r < 16; r++) { pe0[r] = exp2f(s0[r] - mrun); rs += pe0[r]; }
#pragma unroll
    for (int r = 0; r < 16; r++) { pe1[r] = exp2f(s1[r] - mrun); rs += pe1[r]; }
    rs += __shfl_xor(rs, 32);
    lrun += rs;

    // ---- P (C-layout) -> B-fragments, in-register (cvt_pk + half-swap) ----
    int W0[8], W1[8], S0w[8], S1w[8];
#pragma unroll
    for (int j = 0; j < 8; j++) {
      W0[j] = cvtpk(pe0[2 * j], pe0[2 * j + 1]);
      W1[j] = cvtpk(pe1[2 * j], pe1[2 * j + 1]);
    }
#pragma unroll
    for (int j = 0; j < 8; j++) {
      S0w[j] = __shfl_xor(W0[j], 32);
      S1w[j] = __shfl_xor(W1[j], 32);
    }
    bf16x8 pa[4];
    {
      i32x4 w0 = hi ? i32x4{S0w[2], S0w[3], W0[2], W0[3]} : i32x4{W0[0], W0[1], S0w[0], S0w[1]};
      i32x4 w1 = hi ? i32x4{S0w[6], S0w[7], W0[6], W0[7]} : i32x4{W0[4], W0[5], S0w[4], S0w[5]};
      i32x4 w2 = hi ? i32x4{S1w[2], S1w[3], W1[2], W1[3]} : i32x4{W1[0], W1[1], S1w[0], S1w[1]};
      i32x4 w3 = hi ? i32x4{S1w[6], S1w[7], W1[6], W1[7]} : i32x4{W1[4], W1[5], S1w[4], S1w[5]};
      pa[0] = __builtin_bit_cast(bf16x8, w0);
      pa[1] = __builtin_bit_cast(bf16x8, w1);
      pa[2] = __builtin_bit_cast(bf16x8, w2);
      pa[3] = __builtin_bit_cast(bf16x8, w3);
    }

    // ---- PV (swapped): O^T += V^T . P^T ----
#pragma unroll
    for (int ks = 0; ks < 4; ks++) {
      o[0] = __builtin_amdgcn_mfma_f32_32x32x16_bf16(va[ks],     pa[ks], o[0], 0, 0, 0);
      o[1] = __builtin_amdgcn_mfma_f32_32x32x16_bf16(va[4 + ks], pa[ks], o[1], 0, 0, 0);
      o[2] = __builtin_amdgcn_mfma_f32_32x32x16_bf16(vb[ks],     pa[ks], o[2], 0, 0, 0);
      o[3] = __builtin_amdgcn_mfma_f32_32x32x16_bf16(vb[4 + ks], pa[ks], o[3], 0, 0, 0);
    }

    asm volatile("s_waitcnt vmcnt(0)" ::: "memory");
    __syncthreads();
    buf ^= 1;
  }

  // ---- epilogue: O^T -> O via LDS transpose (per-wave region), coalesced store ----
  // regs hold O[q=lanelo][dv=crow]; store LDS as [q][dv] (stride 36) so the
  // float4 read at (q, c..c+3) is layout-consistent.  (round-3 bug: was [dv][q])
  const float inv = 1.f / lrun;
  float* sO = reinterpret_cast<float*>(&sK[0][0]) + wid * 1152;  // 32 rows x 36 floats
#pragma unroll
  for (int dvt = 0; dvt < 4; dvt++) {
    __syncthreads();
#pragma unroll
    for (int r = 0; r < 16; r++) {
      const int dvl = (r & 3) + 8 * (r >> 2) + 4 * hi;  // crow
      sO[lanelo * 36 + dvl] = o[dvt][r] * inv;
    }
    __syncthreads();
#pragma unroll
    for (int p = 0; p < 4; p++) {
      const int q = p * 8 + (lane >> 3), c = (lane & 7) * 4;
      float4 v = *reinterpret_cast<const float4*>(sO + q * 36 + c);
      *reinterpret_cast<float4*>(out + ((size_t)b * 2048 + q0 + q) * 2048 + h * 128 + dvt * 32 + c) = v;
    }
  }
}

// ---------- launcher ----------
extern "C" void kernel_launch(void* const* d_in, const int* in_sizes, int n_in,
                              void* d_out, int out_size, void* d_ws, size_t ws_size,
                              hipStream_t stream) {
  (void)in_sizes; (void)n_in; (void)out_size;
  const float* x     = (const float*)d_in[0];
  const float* W_DKV = (const float*)d_in[1];
  const float* b_DKV = (const float*)d_in[2];
  const float* W_UK  = (const float*)d_in[3];
  const float* b_UK  = (const float*)d_in[4];
  const float* W_UV  = (const float*)d_in[5];
  const float* b_UV  = (const float*)d_in[6];
  const float* W_DQ  = (const float*)d_in[7];
  const float* b_DQ  = (const float*)d_in[8];
  const float* W_UQ  = (const float*)d_in[9];
  const float* b_UQ  = (const float*)d_in[10];
  const float* W_QR  = (const float*)d_in[11];
  const float* b_QR  = (const float*)d_in[12];
  const float* W_KR  = (const float*)d_in[13];
  const float* b_KR  = (const float*)d_in[14];
  float* out = (float*)d_out;

  char* ws = (char*)d_ws;
  unsigned short* xb     = (unsigned short*)(ws + 0);          // [4096][2048] bf16
  unsigned short* WTcat1 = (unsigned short*)(ws + 16777216);   // [1536][2048] (dkv|dq|kr)
  unsigned short* WTcat2 = (unsigned short*)(ws + 23068672);   // [4096][512]  (uk|uv)
  unsigned short* WTcat3 = (unsigned short*)(ws + 27262976);   // [2560][512]  (uq|qr)
  unsigned short* ckv    = (unsigned short*)(ws + 29884416);   // [4096][512]
  unsigned short* cq     = (unsigned short*)(ws + 34078720);   // [4096][512]
  unsigned short* Qbuf   = (unsigned short*)(ws + 38273024);   // (2,16,2048,160) row-major, *QSCALE
  unsigned short* Kfb    = (unsigned short*)(ws + 59244544);   // frag-linear K (32x32x16 A-op)
  unsigned short* Vfb    = (unsigned short*)(ws + 80216064);   // frag-linear V (32x32x16 A-op)
  float*          qrp    = (float*)(ws + 96993280);            // [4096][512] fp32
  float*          krp    = (float*)(ws + 105381888);           // [4096][512] fp32
  if (ws_size < 113770496) return;

  k_cvt_x<<<8192, 256, 0, stream>>>(x, xb, 8388608);

  TwArgs ta;
  ta.W[0] = W_DKV; ta.D[0] = WTcat1;
  ta.W[1] = W_DQ;  ta.D[1] = WTcat1 + (size_t)512 * 2048;
  ta.W[2] = W_KR;  ta.D[2] = WTcat1 + (size_t)1024 * 2048;
  ta.W[3] = W_UK;  ta.D[3] = WTcat2;
  ta.W[4] = W_UV;  ta.D[4] = WTcat2 + (size_t)2048 * 512;
  ta.W[5] = W_UQ;  ta.D[5] = WTcat3;
  ta.W[6] = W_QR;  ta.D[6] = WTcat3 + (size_t)2048 * 512;
  k_tw_all<<<6400, dim3(32, 8), 0, stream>>>(ta);

  // stage 1: x @ [W_DKV | W_DQ | W_KR]
  k_gemm<10><<<dim3(12, 32), 256, 0, stream>>>(xb, WTcat1, b_DKV, b_DQ, b_KR,
                                               ckv, cq, krp, 2048);
  // stage 2: ckv @ [W_UK | W_UV] -> frag K/V ; cq @ [W_UQ | W_QR] -> Q(scaled)/qrp
  k_gemm<11><<<dim3(32, 32), 256, 0, stream>>>(ckv, WTcat2, b_UK, b_UV, nullptr,
                                               Kfb, Vfb, nullptr, 512);
  k_gemm<12><<<dim3(20, 32), 256, 0, stream>>>(cq, WTcat3, b_UQ, b_QR, nullptr,
                                               Qbuf, qrp, nullptr, 512);

  k_rope<<<8192, 256, 0, stream>>>(qrp, krp, Qbuf, Kfb);
  k_attn<<<512, 256, 0, stream>>>(Qbuf, Kfb, Vfb, out);
}